// Round 1
// baseline (348.012 us; speedup 1.0000x reference)
//
#include <hip/hip_runtime.h>
#include <math.h>

#define NJ 24
#define NV 6890
#define NB 10
#define KREAL 217
#define KP 224      // K padded to 7 chunks of 32
#define VPAD 6912   // 108 * 64

__device__ __constant__ int c_path[NJ][9] = {
  {0,0,0,0,0,0,0,0,0},
  {0,1,0,0,0,0,0,0,0},
  {0,2,0,0,0,0,0,0,0},
  {0,3,0,0,0,0,0,0,0},
  {0,1,4,0,0,0,0,0,0},
  {0,2,5,0,0,0,0,0,0},
  {0,3,6,0,0,0,0,0,0},
  {0,1,4,7,0,0,0,0,0},
  {0,2,5,8,0,0,0,0,0},
  {0,3,6,9,0,0,0,0,0},
  {0,1,4,7,10,0,0,0,0},
  {0,2,5,8,11,0,0,0,0},
  {0,3,6,9,12,0,0,0,0},
  {0,3,6,9,13,0,0,0,0},
  {0,3,6,9,14,0,0,0,0},
  {0,3,6,9,12,15,0,0,0},
  {0,3,6,9,13,16,0,0,0},
  {0,3,6,9,14,17,0,0,0},
  {0,3,6,9,13,16,18,0,0},
  {0,3,6,9,14,17,19,0,0},
  {0,3,6,9,13,16,18,20,0},
  {0,3,6,9,14,17,19,21,0},
  {0,3,6,9,13,16,18,20,22},
  {0,3,6,9,14,17,19,21,23}};
__device__ __constant__ int c_plen[NJ] = {1,2,2,2,3,3,3,4,4,4,5,5,5,5,5,6,6,6,7,7,8,8,9,9};

// ---------------------------------------------------------------------------
// Kernel 1: per-batch prep. Grid = B blocks x 64 threads.
// Writes: joints (d_out), glob_rotmats (d_out), A = [R | t'] per (b,j) in ws,
//         coeffT[k][b] (betas ++ pose_feature, zero-padded to KP) in ws.
// ---------------------------------------------------------------------------
__global__ __launch_bounds__(64)
void prep_kernel(const float* __restrict__ pose, const float* __restrict__ betas,
                 const float* __restrict__ trans, const float* __restrict__ J_template,
                 const float* __restrict__ J_shapedirs,
                 float* __restrict__ joints_out, float* __restrict__ glob_out,
                 float* __restrict__ A_ws, float* __restrict__ coeffT, int B)
{
    const int b = blockIdx.x;
    const int t = threadIdx.x;
    __shared__ float s_beta[NB];
    __shared__ float s_rel[NJ][9];
    __shared__ float s_glob[NJ][9];
    __shared__ float s_j[NJ][3];

    if (t < NB) s_beta[t] = betas[b * NB + t];
    __syncthreads();

    if (t < NJ) {
        // Rodrigues
        float rx = pose[b * 72 + t * 3 + 0];
        float ry = pose[b * 72 + t * 3 + 1];
        float rz = pose[b * 72 + t * 3 + 2];
        float th = sqrtf(rx * rx + ry * ry + rz * rz);
        float safe = (th < 1e-8f) ? 1.0f : th;
        float ax = rx / safe, ay = ry / safe, az = rz / safe;
        float s = sinf(th), c = cosf(th), omc = 1.0f - c;
        float aa = ax * ax + ay * ay + az * az;
        // K = [[0,-az,ay],[az,0,-ax],[-ay,ax,0]], K^2 = a a^T - |a|^2 I
        float K[9] = {0.f, -az, ay, az, 0.f, -ax, -ay, ax, 0.f};
        float A2[9] = {ax*ax - aa, ax*ay,      ax*az,
                       ay*ax,      ay*ay - aa, ay*az,
                       az*ax,      az*ay,      az*az - aa};
        #pragma unroll
        for (int r = 0; r < 3; ++r)
            #pragma unroll
            for (int cc = 0; cc < 3; ++cc)
                s_rel[t][r * 3 + cc] = ((r == cc) ? 1.0f : 0.0f)
                                     + s * K[r * 3 + cc] + omc * A2[r * 3 + cc];
        // shaped joint location
        #pragma unroll
        for (int cc = 0; cc < 3; ++cc) {
            float acc = J_template[t * 3 + cc];
            #pragma unroll
            for (int q = 0; q < NB; ++q)
                acc = fmaf(J_shapedirs[(t * 3 + cc) * NB + q], s_beta[q], acc);
            s_j[t][cc] = acc;
        }
    }
    __syncthreads();

    if (t < NJ) {
        // global rotation = product of rel along ancestor path
        const int L = c_plen[t];
        float G[9];
        #pragma unroll
        for (int e = 0; e < 9; ++e) G[e] = s_rel[0][e];   // path[0] == 0 always
        for (int sIdx = 1; sIdx < L; ++sIdx) {
            const int p = c_path[t][sIdx];
            float Tn[9];
            #pragma unroll
            for (int r = 0; r < 3; ++r)
                #pragma unroll
                for (int cc = 0; cc < 3; ++cc)
                    Tn[r * 3 + cc] = G[r * 3 + 0] * s_rel[p][0 * 3 + cc]
                                   + G[r * 3 + 1] * s_rel[p][1 * 3 + cc]
                                   + G[r * 3 + 2] * s_rel[p][2 * 3 + cc];
            #pragma unroll
            for (int e = 0; e < 9; ++e) G[e] = Tn[e];
        }
        #pragma unroll
        for (int e = 0; e < 9; ++e) s_glob[t][e] = G[e];
        #pragma unroll
        for (int e = 0; e < 9; ++e) glob_out[(size_t)b * 216 + t * 9 + e] = G[e];
    }
    __syncthreads();

    if (t < NJ) {
        // global joint position via path walk
        const int L = c_plen[t];
        float px = s_j[0][0], py = s_j[0][1], pz = s_j[0][2];
        for (int sIdx = 1; sIdx < L; ++sIdx) {
            const int pk = c_path[t][sIdx];
            const int pp = c_path[t][sIdx - 1];
            float bx = s_j[pk][0] - s_j[pp][0];
            float by = s_j[pk][1] - s_j[pp][1];
            float bz = s_j[pk][2] - s_j[pp][2];
            px += s_glob[pp][0] * bx + s_glob[pp][1] * by + s_glob[pp][2] * bz;
            py += s_glob[pp][3] * bx + s_glob[pp][4] * by + s_glob[pp][5] * bz;
            pz += s_glob[pp][6] * bx + s_glob[pp][7] * by + s_glob[pp][8] * bz;
        }
        const float tx = trans[b * 3 + 0], ty = trans[b * 3 + 1], tz = trans[b * 3 + 2];
        // joints output = pos + trans
        joints_out[(size_t)b * 72 + t * 3 + 0] = px + tx;
        joints_out[(size_t)b * 72 + t * 3 + 1] = py + ty;
        joints_out[(size_t)b * 72 + t * 3 + 2] = pz + tz;
        // affine A = [ G | pos - G*j + trans ]  (trans folded: sum_j w = 1)
        const float jx = s_j[t][0], jy = s_j[t][1], jz = s_j[t][2];
        float T0 = px - (s_glob[t][0] * jx + s_glob[t][1] * jy + s_glob[t][2] * jz) + tx;
        float T1 = py - (s_glob[t][3] * jx + s_glob[t][4] * jy + s_glob[t][5] * jz) + ty;
        float T2 = pz - (s_glob[t][6] * jx + s_glob[t][7] * jy + s_glob[t][8] * jz) + tz;
        float* Ab = A_ws + ((size_t)b * NJ + t) * 12;
        Ab[0]  = s_glob[t][0]; Ab[1]  = s_glob[t][1]; Ab[2]  = s_glob[t][2]; Ab[3]  = T0;
        Ab[4]  = s_glob[t][3]; Ab[5]  = s_glob[t][4]; Ab[6]  = s_glob[t][5]; Ab[7]  = T1;
        Ab[8]  = s_glob[t][6]; Ab[9]  = s_glob[t][7]; Ab[10] = s_glob[t][8]; Ab[11] = T2;
    }

    // coefficient vector, K-transposed: coeffT[k][b]
    for (int k = t; k < KP; k += 64) {
        float val;
        if (k < NB) val = s_beta[k];
        else if (k < KREAL) {
            int p = k - NB;
            int jj = 1 + p / 9;
            int e = p % 9;
            val = s_rel[jj][e];
        } else val = 0.0f;
        coeffT[(size_t)k * B + b] = val;
    }
}

// ---------------------------------------------------------------------------
// Kernel 2: pack shapedirs(V,3,10) ++ posedirs(V,3,207) -> dirsT[KP][3][VPAD]
// Grid (108 vtiles, 7 ktiles, 3 c), 256 threads. Zero-fills padding.
// ---------------------------------------------------------------------------
__global__ __launch_bounds__(256)
void transpose_kernel(const float* __restrict__ shapedirs,
                      const float* __restrict__ posedirs,
                      float* __restrict__ dirsT)
{
    __shared__ float tile[64][33];
    const int vb = blockIdx.x * 64;
    const int kb = blockIdx.y * 32;
    const int c  = blockIdx.z;
    const int t  = threadIdx.x;
    const int kl = t & 31;
    const int vl0 = t >> 5;
    const int k = kb + kl;
    #pragma unroll
    for (int i = 0; i < 8; ++i) {
        const int vl = vl0 + i * 8;
        const int v = vb + vl;
        float val = 0.0f;
        if (v < NV && k < KREAL) {
            val = (k < NB) ? shapedirs[(size_t)v * 30 + c * NB + k]
                           : posedirs[(size_t)v * 621 + c * 207 + (k - NB)];
        }
        tile[vl][kl] = val;
    }
    __syncthreads();
    const int vl = t & 63;
    const int kl0 = t >> 6;
    #pragma unroll
    for (int i = 0; i < 8; ++i) {
        const int kk = kl0 + i * 4;
        dirsT[((size_t)(kb + kk) * 3 + c) * VPAD + vb + vl] = tile[vl][kk];
    }
}

// ---------------------------------------------------------------------------
// Kernel 3: fused v_posed GEMM + LBS.
// Grid (B/64 btiles, 108 vtiles), 256 threads. Thread: vertex=lane, 16 batches.
// ---------------------------------------------------------------------------
__global__ __launch_bounds__(256)
void vert_kernel(const float* __restrict__ dirsT, const float* __restrict__ coeffT,
                 const float* __restrict__ A_ws, const float* __restrict__ v_template,
                 const float* __restrict__ weights, float* __restrict__ vert_out, int B)
{
    __shared__ float smem[12288];           // [0,6144): dirs chunk; later vp[3][64][64]
    float* sdirs = smem;

    const int lane = threadIdx.x & 63;
    const int bg = __builtin_amdgcn_readfirstlane((int)threadIdx.x >> 6);
    const int vb = blockIdx.y * 64;
    const int bbase = blockIdx.x * 64 + bg * 16;

    float acc[3][16];
    #pragma unroll
    for (int cdim = 0; cdim < 3; ++cdim)
        #pragma unroll
        for (int q = 0; q < 16; ++q) acc[cdim][q] = 0.0f;

    for (int kb = 0; kb < KP; kb += 32) {
        __syncthreads();
        // stage dirs chunk: 96 rows (k-major,c) x 64 v, as float4s
        #pragma unroll
        for (int i = 0; i < 6; ++i) {
            const int flat4 = i * 256 + (int)threadIdx.x;  // 0..1535
            const int row = flat4 >> 4;                    // 0..95
            const int v4 = (flat4 & 15) << 2;              // 0..60
            const float4 d = *(const float4*)(dirsT + ((size_t)kb * 3 + row) * VPAD + vb + v4);
            *(float4*)(sdirs + row * 64 + v4) = d;
        }
        __syncthreads();
        #pragma unroll 4
        for (int kl = 0; kl < 32; ++kl) {
            const float d0 = sdirs[(kl * 3 + 0) * 64 + lane];
            const float d1 = sdirs[(kl * 3 + 1) * 64 + lane];
            const float d2 = sdirs[(kl * 3 + 2) * 64 + lane];
            const float* crow = coeffT + (size_t)(kb + kl) * B + bbase;  // wave-uniform
            const float4 c0 = *(const float4*)(crow + 0);
            const float4 c1 = *(const float4*)(crow + 4);
            const float4 c2 = *(const float4*)(crow + 8);
            const float4 c3 = *(const float4*)(crow + 12);
            float cf[16];
            cf[0] = c0.x; cf[1] = c0.y; cf[2]  = c0.z; cf[3]  = c0.w;
            cf[4] = c1.x; cf[5] = c1.y; cf[6]  = c1.z; cf[7]  = c1.w;
            cf[8] = c2.x; cf[9] = c2.y; cf[10] = c2.z; cf[11] = c2.w;
            cf[12] = c3.x; cf[13] = c3.y; cf[14] = c3.z; cf[15] = c3.w;
            #pragma unroll
            for (int q = 0; q < 16; ++q) {
                acc[0][q] = fmaf(d0, cf[q], acc[0][q]);
                acc[1][q] = fmaf(d1, cf[q], acc[1][q]);
                acc[2][q] = fmaf(d2, cf[q], acc[2][q]);
            }
        }
    }

    // spill acc to LDS so the batch loop below can index it at runtime
    __syncthreads();
    #pragma unroll
    for (int cdim = 0; cdim < 3; ++cdim)
        #pragma unroll
        for (int q = 0; q < 16; ++q)
            smem[(cdim * 64 + bg * 16 + q) * 64 + lane] = acc[cdim][q];
    __syncthreads();

    const int v = vb + lane;
    if (v < NV) {
        float w[NJ];
        const float4* wp = (const float4*)(weights + (size_t)v * NJ);
        #pragma unroll
        for (int q = 0; q < 6; ++q) {
            const float4 t4 = wp[q];
            w[q * 4 + 0] = t4.x; w[q * 4 + 1] = t4.y; w[q * 4 + 2] = t4.z; w[q * 4 + 3] = t4.w;
        }
        const float vt0 = v_template[(size_t)v * 3 + 0];
        const float vt1 = v_template[(size_t)v * 3 + 1];
        const float vt2 = v_template[(size_t)v * 3 + 2];

        for (int i = 0; i < 16; ++i) {
            const int b = bbase + i;
            const float4* Ab = (const float4*)(A_ws + (size_t)b * (NJ * 12));  // uniform
            float R0 = 0.f, R1 = 0.f, R2 = 0.f, R3 = 0.f, R4 = 0.f, R5 = 0.f,
                  R6 = 0.f, R7 = 0.f, R8 = 0.f, T0 = 0.f, T1 = 0.f, T2 = 0.f;
            #pragma unroll
            for (int jj = 0; jj < NJ; ++jj) {
                const float wj = w[jj];
                const float4 a0 = Ab[jj * 3 + 0];
                const float4 a1 = Ab[jj * 3 + 1];
                const float4 a2 = Ab[jj * 3 + 2];
                R0 = fmaf(wj, a0.x, R0); R1 = fmaf(wj, a0.y, R1); R2 = fmaf(wj, a0.z, R2); T0 = fmaf(wj, a0.w, T0);
                R3 = fmaf(wj, a1.x, R3); R4 = fmaf(wj, a1.y, R4); R5 = fmaf(wj, a1.z, R5); T1 = fmaf(wj, a1.w, T1);
                R6 = fmaf(wj, a2.x, R6); R7 = fmaf(wj, a2.y, R7); R8 = fmaf(wj, a2.z, R8); T2 = fmaf(wj, a2.w, T2);
            }
            const int lb = bg * 16 + i;
            const float vp0 = vt0 + smem[(0 * 64 + lb) * 64 + lane];
            const float vp1 = vt1 + smem[(1 * 64 + lb) * 64 + lane];
            const float vp2 = vt2 + smem[(2 * 64 + lb) * 64 + lane];
            const float o0 = R0 * vp0 + R1 * vp1 + R2 * vp2 + T0;
            const float o1 = R3 * vp0 + R4 * vp1 + R5 * vp2 + T1;
            const float o2 = R6 * vp0 + R7 * vp1 + R8 * vp2 + T2;
            const size_t off = (size_t)b * (NV * 3) + (size_t)v * 3;
            vert_out[off + 0] = o0;
            vert_out[off + 1] = o1;
            vert_out[off + 2] = o2;
        }
    }
}

// ---------------------------------------------------------------------------
extern "C" void kernel_launch(void* const* d_in, const int* in_sizes, int n_in,
                              void* d_out, int out_size, void* d_ws, size_t ws_size,
                              hipStream_t stream) {
    const float* pose        = (const float*)d_in[0];
    const float* betas       = (const float*)d_in[1];
    const float* trans       = (const float*)d_in[2];
    const float* v_template  = (const float*)d_in[3];
    const float* shapedirs   = (const float*)d_in[4];
    const float* posedirs    = (const float*)d_in[5];
    const float* J_template  = (const float*)d_in[6];
    const float* J_shapedirs = (const float*)d_in[7];
    const float* weights     = (const float*)d_in[8];
    const int B = in_sizes[0] / 72;   // 1024

    float* out = (float*)d_out;
    float* joints_out = out;                                   // B*72
    float* vert_out   = out + (size_t)B * 72;                  // B*NV*3
    float* glob_out   = out + (size_t)B * 72 + (size_t)B * NV * 3;  // B*216

    float* A_ws   = (float*)d_ws;                              // B*288 floats
    float* coeffT = A_ws + (size_t)B * 288;                    // KP*B floats
    float* dirsT  = coeffT + (size_t)KP * B;                   // KP*3*VPAD floats

    transpose_kernel<<<dim3(108, 7, 3), 256, 0, stream>>>(shapedirs, posedirs, dirsT);
    prep_kernel<<<dim3(B), 64, 0, stream>>>(pose, betas, trans, J_template, J_shapedirs,
                                            joints_out, glob_out, A_ws, coeffT, B);
    vert_kernel<<<dim3(B / 64, 108), 256, 0, stream>>>(dirsT, coeffT, A_ws, v_template,
                                                       weights, vert_out, B);
}

// Round 3
// 247.371 us; speedup vs baseline: 1.4068x; 1.4068x over previous
//
#include <hip/hip_runtime.h>
#include <math.h>

#define NJ 24
#define NV 6890
#define NB 10
#define KREAL 217
#define KP 224      // K padded to 7 chunks of 32
#define NVT 432     // ceil(NV/16) vertex tiles of 16

typedef __attribute__((ext_vector_type(8))) short bf16x8;
typedef __attribute__((ext_vector_type(8))) unsigned short u16x8;
typedef __attribute__((ext_vector_type(4))) float f32x4;

__device__ __forceinline__ unsigned short f2bf(float x) {
    unsigned int u = __float_as_uint(x);
    u += 0x7fffu + ((u >> 16) & 1u);
    return (unsigned short)(u >> 16);
}

__device__ __constant__ int c_path[NJ][9] = {
  {0,0,0,0,0,0,0,0,0},
  {0,1,0,0,0,0,0,0,0},
  {0,2,0,0,0,0,0,0,0},
  {0,3,0,0,0,0,0,0,0},
  {0,1,4,0,0,0,0,0,0},
  {0,2,5,0,0,0,0,0,0},
  {0,3,6,0,0,0,0,0,0},
  {0,1,4,7,0,0,0,0,0},
  {0,2,5,8,0,0,0,0,0},
  {0,3,6,9,0,0,0,0,0},
  {0,1,4,7,10,0,0,0,0},
  {0,2,5,8,11,0,0,0,0},
  {0,3,6,9,12,0,0,0,0},
  {0,3,6,9,13,0,0,0,0},
  {0,3,6,9,14,0,0,0,0},
  {0,3,6,9,12,15,0,0,0},
  {0,3,6,9,13,16,0,0,0},
  {0,3,6,9,14,17,0,0,0},
  {0,3,6,9,13,16,18,0,0},
  {0,3,6,9,14,17,19,0,0},
  {0,3,6,9,13,16,18,20,0},
  {0,3,6,9,14,17,19,21,0},
  {0,3,6,9,13,16,18,20,22},
  {0,3,6,9,14,17,19,21,23}};
__device__ __constant__ int c_plen[NJ] = {1,2,2,2,3,3,3,4,4,4,5,5,5,5,5,6,6,6,7,7,8,8,9,9};

// ---------------------------------------------------------------------------
// Kernel 1: pack dirs into MFMA A-fragment order (bf16).
// dirsF[kt][c][vtg][lane] (float4): v = vtg*16+(lane&15), k = kt*32+(lane>>4)*8+i
// Grid (108, 7) x 256.
// ---------------------------------------------------------------------------
__global__ __launch_bounds__(256)
void pack_kernel(const float* __restrict__ shapedirs, const float* __restrict__ posedirs,
                 unsigned short* __restrict__ dirsF)
{
    const int t = threadIdx.x;
    const int vt = t >> 6;           // 0..3
    const int lane = t & 63;
    const int kg = lane >> 4;
    const int vsub = lane & 15;
    const int vtg = blockIdx.x * 4 + vt;
    const int v = vtg * 16 + vsub;
    const int kt = blockIdx.y;

    #pragma unroll
    for (int c = 0; c < 3; ++c) {
        u16x8 o;
        #pragma unroll
        for (int i = 0; i < 8; ++i) {
            const int k = kt * 32 + kg * 8 + i;
            float val = 0.f;
            if (v < NV && k < KREAL)
                val = (k < NB) ? shapedirs[(size_t)v * 30 + c * NB + k]
                               : posedirs[(size_t)v * 621 + c * 207 + (k - NB)];
            o[i] = f2bf(val);
        }
        *(u16x8*)&dirsF[(((size_t)(kt * 3 + c) * NVT + vtg) * 64 + lane) * 8] = o;
    }
}

// ---------------------------------------------------------------------------
// Kernel 2: per-batch prep. Grid = B blocks x 64 threads.
// Writes joints & glob_rotmats (d_out), A_ws fp32 [R|T] rows (round-1 format),
// coeffF (bf16 B-frags of betas++pose_feature padded to 224).
// ---------------------------------------------------------------------------
__global__ __launch_bounds__(64)
void prep_kernel(const float* __restrict__ pose, const float* __restrict__ betas,
                 const float* __restrict__ trans, const float* __restrict__ J_template,
                 const float* __restrict__ J_shapedirs,
                 float* __restrict__ joints_out, float* __restrict__ glob_out,
                 float* __restrict__ A_ws, unsigned short* __restrict__ coeffF, int B)
{
    const int b = blockIdx.x;
    const int t = threadIdx.x;
    __shared__ float s_beta[NB];
    __shared__ float s_rel[NJ][9];
    __shared__ float s_glob[NJ][9];
    __shared__ float s_j[NJ][3];

    if (t < NB) s_beta[t] = betas[b * NB + t];
    __syncthreads();

    if (t < NJ) {
        float rx = pose[b * 72 + t * 3 + 0];
        float ry = pose[b * 72 + t * 3 + 1];
        float rz = pose[b * 72 + t * 3 + 2];
        float th = sqrtf(rx * rx + ry * ry + rz * rz);
        float safe = (th < 1e-8f) ? 1.0f : th;
        float ax = rx / safe, ay = ry / safe, az = rz / safe;
        float s = sinf(th), c = cosf(th), omc = 1.0f - c;
        float aa = ax * ax + ay * ay + az * az;
        float K[9] = {0.f, -az, ay, az, 0.f, -ax, -ay, ax, 0.f};
        float A2[9] = {ax*ax - aa, ax*ay,      ax*az,
                       ay*ax,      ay*ay - aa, ay*az,
                       az*ax,      az*ay,      az*az - aa};
        #pragma unroll
        for (int r = 0; r < 3; ++r)
            #pragma unroll
            for (int cc = 0; cc < 3; ++cc)
                s_rel[t][r * 3 + cc] = ((r == cc) ? 1.0f : 0.0f)
                                     + s * K[r * 3 + cc] + omc * A2[r * 3 + cc];
        #pragma unroll
        for (int cc = 0; cc < 3; ++cc) {
            float acc = J_template[t * 3 + cc];
            #pragma unroll
            for (int q = 0; q < NB; ++q)
                acc = fmaf(J_shapedirs[(t * 3 + cc) * NB + q], s_beta[q], acc);
            s_j[t][cc] = acc;
        }
    }
    __syncthreads();

    if (t < NJ) {
        const int L = c_plen[t];
        float G[9];
        #pragma unroll
        for (int e = 0; e < 9; ++e) G[e] = s_rel[0][e];
        for (int sIdx = 1; sIdx < L; ++sIdx) {
            const int p = c_path[t][sIdx];
            float Tn[9];
            #pragma unroll
            for (int r = 0; r < 3; ++r)
                #pragma unroll
                for (int cc = 0; cc < 3; ++cc)
                    Tn[r * 3 + cc] = G[r * 3 + 0] * s_rel[p][0 * 3 + cc]
                                   + G[r * 3 + 1] * s_rel[p][1 * 3 + cc]
                                   + G[r * 3 + 2] * s_rel[p][2 * 3 + cc];
            #pragma unroll
            for (int e = 0; e < 9; ++e) G[e] = Tn[e];
        }
        #pragma unroll
        for (int e = 0; e < 9; ++e) s_glob[t][e] = G[e];
        #pragma unroll
        for (int e = 0; e < 9; ++e) glob_out[(size_t)b * 216 + t * 9 + e] = G[e];
    }
    __syncthreads();

    if (t < NJ) {
        const int L = c_plen[t];
        float px = s_j[0][0], py = s_j[0][1], pz = s_j[0][2];
        for (int sIdx = 1; sIdx < L; ++sIdx) {
            const int pk = c_path[t][sIdx];
            const int pp = c_path[t][sIdx - 1];
            float bx = s_j[pk][0] - s_j[pp][0];
            float by = s_j[pk][1] - s_j[pp][1];
            float bz = s_j[pk][2] - s_j[pp][2];
            px += s_glob[pp][0] * bx + s_glob[pp][1] * by + s_glob[pp][2] * bz;
            py += s_glob[pp][3] * bx + s_glob[pp][4] * by + s_glob[pp][5] * bz;
            pz += s_glob[pp][6] * bx + s_glob[pp][7] * by + s_glob[pp][8] * bz;
        }
        const float tx = trans[b * 3 + 0], ty = trans[b * 3 + 1], tz = trans[b * 3 + 2];
        joints_out[(size_t)b * 72 + t * 3 + 0] = px + tx;
        joints_out[(size_t)b * 72 + t * 3 + 1] = py + ty;
        joints_out[(size_t)b * 72 + t * 3 + 2] = pz + tz;
        const float jx = s_j[t][0], jy = s_j[t][1], jz = s_j[t][2];
        float T0 = px - (s_glob[t][0] * jx + s_glob[t][1] * jy + s_glob[t][2] * jz) + tx;
        float T1 = py - (s_glob[t][3] * jx + s_glob[t][4] * jy + s_glob[t][5] * jz) + ty;
        float T2 = pz - (s_glob[t][6] * jx + s_glob[t][7] * jy + s_glob[t][8] * jz) + tz;
        float* Ab = A_ws + ((size_t)b * NJ + t) * 12;
        Ab[0]  = s_glob[t][0]; Ab[1]  = s_glob[t][1]; Ab[2]  = s_glob[t][2]; Ab[3]  = T0;
        Ab[4]  = s_glob[t][3]; Ab[5]  = s_glob[t][4]; Ab[6]  = s_glob[t][5]; Ab[7]  = T1;
        Ab[8]  = s_glob[t][6]; Ab[9]  = s_glob[t][7]; Ab[10] = s_glob[t][8]; Ab[11] = T2;
    }
    __syncthreads();

    const int btg = b >> 4, bl = b & 15;
    // coeffF B-frags: value = coeff[k][b], lane = kg*16 + bl, k = kt*32+kg*8+i
    for (int k = t; k < KP; k += 64) {
        float val;
        if (k < NB) val = s_beta[k];
        else if (k < KREAL) { const int p2 = k - NB; val = s_rel[1 + p2 / 9][p2 % 9]; }
        else val = 0.f;
        const int kt = k >> 5, kg = (k >> 3) & 3, i = k & 7;
        coeffF[(((size_t)kt * (B >> 4) + btg) * 64 + kg * 16 + bl) * 8 + i] = f2bf(val);
    }
}

// ---------------------------------------------------------------------------
// Kernel 3: MFMA v_posed GEMM (K=224) + fp32 scalar LBS (round-1-verified path).
// Grid (B/64, 108) x 256 threads (4 waves). Wave w: vtile w, all 4 b-tiles.
// ---------------------------------------------------------------------------
__global__ __launch_bounds__(256)
void vert_kernel(const float4* __restrict__ dirsF, const float4* __restrict__ coeffF,
                 const float* __restrict__ A_ws, const float* __restrict__ v_template,
                 const float* __restrict__ weights, float* __restrict__ vert_out, int B)
{
    __shared__ float smem[13056];   // [0,3072) floats: dirs chunk; later vp[3*64][68]
    const int tid  = threadIdx.x;
    const int lane = tid & 63;
    const int w    = __builtin_amdgcn_readfirstlane(tid >> 6);   // 0..3
    const int vt   = w;
    const int vb4  = blockIdx.y * 4;     // global vtile base
    const int bblk = blockIdx.x;
    const int nbt  = B >> 4;

    f32x4 acc[3][4];
    #pragma unroll
    for (int c = 0; c < 3; ++c)
        #pragma unroll
        for (int bt = 0; bt < 4; ++bt) {
            acc[c][bt][0] = 0.f; acc[c][bt][1] = 0.f; acc[c][bt][2] = 0.f; acc[c][bt][3] = 0.f;
        }

    for (int kt = 0; kt < 7; ++kt) {
        __syncthreads();
        // stage 768 float4 of dirs chunk (12 KB): [c][vtl][lane]
        #pragma unroll
        for (int s = 0; s < 3; ++s) {
            const int row = s * 256 + tid;
            const int ch = row >> 6, l2 = row & 63;
            *(float4*)&smem[row * 4] =
                dirsF[((size_t)(kt * 3 + (ch >> 2)) * NVT + vb4 + (ch & 3)) * 64 + l2];
        }
        __syncthreads();
        bf16x8 bq[4];
        #pragma unroll
        for (int bt = 0; bt < 4; ++bt)
            bq[bt] = *(const bf16x8*)&coeffF[((size_t)kt * nbt + bblk * 4 + bt) * 64 + lane];
        #pragma unroll
        for (int c = 0; c < 3; ++c) {
            const bf16x8 a = *(const bf16x8*)&smem[((c * 4 + vt) * 64 + lane) * 4];
            #pragma unroll
            for (int bt = 0; bt < 4; ++bt)
                acc[c][bt] = __builtin_amdgcn_mfma_f32_16x16x32_bf16(a, bq[bt], acc[c][bt], 0, 0, 0);
        }
    }

    // add v_template: C-frag rows v = (vb4+vt)*16 + (lane>>4)*4 + r
    const int vrow0 = (vb4 + vt) * 16 + ((lane >> 4) << 2);
    #pragma unroll
    for (int c = 0; c < 3; ++c) {
        float tv[4];
        #pragma unroll
        for (int r = 0; r < 4; ++r) {
            const int v = vrow0 + r;
            tv[r] = (v < NV) ? v_template[(size_t)v * 3 + c] : 0.f;
        }
        #pragma unroll
        for (int bt = 0; bt < 4; ++bt) {
            acc[c][bt][0] += tv[0]; acc[c][bt][1] += tv[1];
            acc[c][bt][2] += tv[2]; acc[c][bt][3] += tv[3];
        }
    }

    __syncthreads();   // all waves done reading dirs LDS
    // transpose C-frags into vp[c][b_local][v_local], row stride 68 (2-way max conflict)
    #pragma unroll
    for (int c = 0; c < 3; ++c)
        #pragma unroll
        for (int bt = 0; bt < 4; ++bt) {
            const int bl = bt * 16 + (lane & 15);
            const int vl = vt * 16 + ((lane >> 4) << 2);
            #pragma unroll
            for (int r = 0; r < 4; ++r)
                smem[(c * 64 + bl) * 68 + vl + r] = acc[c][bt][r];
        }
    __syncthreads();

    // ---- fp32 scalar LBS (round-1-verified) ----
    const int v = vb4 * 16 + lane;
    if (v < NV) {
        float wj[NJ];
        const float4* wp = (const float4*)(weights + (size_t)v * NJ);
        #pragma unroll
        for (int q = 0; q < 6; ++q) {
            const float4 t4 = wp[q];
            wj[q * 4 + 0] = t4.x; wj[q * 4 + 1] = t4.y; wj[q * 4 + 2] = t4.z; wj[q * 4 + 3] = t4.w;
        }
        for (int i = 0; i < 16; ++i) {
            const int b = bblk * 64 + w * 16 + i;
            const float4* Ab = (const float4*)(A_ws + (size_t)b * (NJ * 12));  // wave-uniform
            float R0 = 0.f, R1 = 0.f, R2 = 0.f, R3 = 0.f, R4 = 0.f, R5 = 0.f,
                  R6 = 0.f, R7 = 0.f, R8 = 0.f, T0 = 0.f, T1 = 0.f, T2 = 0.f;
            #pragma unroll
            for (int jj = 0; jj < NJ; ++jj) {
                const float wv = wj[jj];
                const float4 a0 = Ab[jj * 3 + 0];
                const float4 a1 = Ab[jj * 3 + 1];
                const float4 a2 = Ab[jj * 3 + 2];
                R0 = fmaf(wv, a0.x, R0); R1 = fmaf(wv, a0.y, R1); R2 = fmaf(wv, a0.z, R2); T0 = fmaf(wv, a0.w, T0);
                R3 = fmaf(wv, a1.x, R3); R4 = fmaf(wv, a1.y, R4); R5 = fmaf(wv, a1.z, R5); T1 = fmaf(wv, a1.w, T1);
                R6 = fmaf(wv, a2.x, R6); R7 = fmaf(wv, a2.y, R7); R8 = fmaf(wv, a2.z, R8); T2 = fmaf(wv, a2.w, T2);
            }
            const int bl = w * 16 + i;
            const float vp0 = smem[(0 * 64 + bl) * 68 + lane];
            const float vp1 = smem[(1 * 64 + bl) * 68 + lane];
            const float vp2 = smem[(2 * 64 + bl) * 68 + lane];
            const float o0 = R0 * vp0 + R1 * vp1 + R2 * vp2 + T0;
            const float o1 = R3 * vp0 + R4 * vp1 + R5 * vp2 + T1;
            const float o2 = R6 * vp0 + R7 * vp1 + R8 * vp2 + T2;
            const size_t off = (size_t)b * (NV * 3) + (size_t)v * 3;
            vert_out[off + 0] = o0;
            vert_out[off + 1] = o1;
            vert_out[off + 2] = o2;
        }
    }
}

// ---------------------------------------------------------------------------
extern "C" void kernel_launch(void* const* d_in, const int* in_sizes, int n_in,
                              void* d_out, int out_size, void* d_ws, size_t ws_size,
                              hipStream_t stream) {
    const float* pose        = (const float*)d_in[0];
    const float* betas       = (const float*)d_in[1];
    const float* trans       = (const float*)d_in[2];
    const float* v_template  = (const float*)d_in[3];
    const float* shapedirs   = (const float*)d_in[4];
    const float* posedirs    = (const float*)d_in[5];
    const float* J_template  = (const float*)d_in[6];
    const float* J_shapedirs = (const float*)d_in[7];
    const float* weights     = (const float*)d_in[8];
    const int B = in_sizes[0] / 72;   // 1024

    float* out = (float*)d_out;
    float* joints_out = out;                                        // B*72
    float* vert_out   = out + (size_t)B * 72;                       // B*NV*3
    float* glob_out   = out + (size_t)B * 72 + (size_t)B * NV * 3;  // B*216

    char* ws = (char*)d_ws;
    const size_t a_bytes     = (size_t)B * 288 * 4;                  // 1,179,648
    const size_t coeff_bytes = (size_t)7 * (B >> 4) * 64 * 16;       // 458,752
    float*          A_ws   = (float*)ws;
    unsigned short* coeffF = (unsigned short*)(ws + a_bytes);
    unsigned short* dirsF  = (unsigned short*)(ws + a_bytes + coeff_bytes);

    pack_kernel<<<dim3(108, 7), 256, 0, stream>>>(shapedirs, posedirs, dirsF);
    prep_kernel<<<dim3(B), 64, 0, stream>>>(pose, betas, trans, J_template, J_shapedirs,
                                            joints_out, glob_out, A_ws, coeffF, B);
    vert_kernel<<<dim3(B / 64, 108), 256, 0, stream>>>((const float4*)dirsF, (const float4*)coeffF,
                                                       A_ws, v_template, weights, vert_out, B);
}

// Round 6
// 221.402 us; speedup vs baseline: 1.5719x; 1.1173x over previous
//
#include <hip/hip_runtime.h>
#include <math.h>

#define NJ 24
#define NV 6890
#define NB 10
#define KREAL 217
#define KP 224      // K padded to 7 chunks of 32
#define NVT 432     // ceil(NV/16) vertex tiles of 16

typedef __attribute__((ext_vector_type(8))) short bf16x8;
typedef __attribute__((ext_vector_type(8))) unsigned short u16x8;
typedef __attribute__((ext_vector_type(4))) float f32x4;

__device__ __forceinline__ unsigned short f2bf(float x) {
    unsigned int u = __float_as_uint(x);
    u += 0x7fffu + ((u >> 16) & 1u);
    return (unsigned short)(u >> 16);
}

__device__ __constant__ int c_path[NJ][9] = {
  {0,0,0,0,0,0,0,0,0},
  {0,1,0,0,0,0,0,0,0},
  {0,2,0,0,0,0,0,0,0},
  {0,3,0,0,0,0,0,0,0},
  {0,1,4,0,0,0,0,0,0},
  {0,2,5,0,0,0,0,0,0},
  {0,3,6,0,0,0,0,0,0},
  {0,1,4,7,0,0,0,0,0},
  {0,2,5,8,0,0,0,0,0},
  {0,3,6,9,0,0,0,0,0},
  {0,1,4,7,10,0,0,0,0},
  {0,2,5,8,11,0,0,0,0},
  {0,3,6,9,12,0,0,0,0},
  {0,3,6,9,13,0,0,0,0},
  {0,3,6,9,14,0,0,0,0},
  {0,3,6,9,12,15,0,0,0},
  {0,3,6,9,13,16,0,0,0},
  {0,3,6,9,14,17,0,0,0},
  {0,3,6,9,13,16,18,0,0},
  {0,3,6,9,14,17,19,0,0},
  {0,3,6,9,13,16,18,20,0},
  {0,3,6,9,14,17,19,21,0},
  {0,3,6,9,13,16,18,20,22},
  {0,3,6,9,14,17,19,21,23}};
__device__ __constant__ int c_plen[NJ] = {1,2,2,2,3,3,3,4,4,4,5,5,5,5,5,6,6,6,7,7,8,8,9,9};

// ---------------------------------------------------------------------------
// Kernel 1: coalesced pack of dirs into certified MFMA A-fragment order.
// Block = one 16-vertex tile (vtg). Phase 1: load rows k-contiguously
// (coalesced) into bf16 LDS tile [16][3][240]. Phase 2: emit fragments.
// dirsF[kt][c][vtg][lane][8i] : v = vtg*16+(lane&15), k = kt*32+(lane>>4)*8+i
// Grid 432 x 256.
// ---------------------------------------------------------------------------
__global__ __launch_bounds__(256)
void pack_kernel(const float* __restrict__ shapedirs, const float* __restrict__ posedirs,
                 unsigned short* __restrict__ dirsF)
{
    __shared__ unsigned short tile[16][3][240];
    const int t = threadIdx.x;
    const int vtg = blockIdx.x;

    // Phase 1: fill tile[v_l][c][k] for k in [0, KP), coalesced along k.
    for (int idx = t; idx < 16 * 3 * KP; idx += 256) {
        const int v_l = idx / (3 * KP);
        const int rem = idx - v_l * (3 * KP);
        const int c = rem / KP;
        const int k = rem - c * KP;
        const int v = vtg * 16 + v_l;
        float val = 0.f;
        if (v < NV && k < KREAL)
            val = (k < NB) ? shapedirs[(size_t)v * 30 + c * NB + k]
                           : posedirs[(size_t)v * 621 + c * 207 + (k - NB)];
        tile[v_l][c][k] = f2bf(val);
    }
    __syncthreads();

    // Phase 2: emit fragments. 21 (kt,c) pairs over 4 waves.
    const int lane = t & 63;
    const int w = t >> 6;
    const int kg = lane >> 4;
    const int vsub = lane & 15;
    for (int j2 = w; j2 < 21; j2 += 4) {
        const int kt = j2 / 3;
        const int c = j2 - kt * 3;
        const u16x8 o = *(const u16x8*)&tile[vsub][c][kt * 32 + kg * 8];
        *(u16x8*)&dirsF[(((size_t)(kt * 3 + c) * NVT + vtg) * 64 + lane) * 8] = o;
    }
}

// ---------------------------------------------------------------------------
// Kernel 2: per-batch prep (certified, verbatim from R3). Grid = B x 64.
// ---------------------------------------------------------------------------
__global__ __launch_bounds__(64)
void prep_kernel(const float* __restrict__ pose, const float* __restrict__ betas,
                 const float* __restrict__ trans, const float* __restrict__ J_template,
                 const float* __restrict__ J_shapedirs,
                 float* __restrict__ joints_out, float* __restrict__ glob_out,
                 float* __restrict__ A_ws, unsigned short* __restrict__ coeffF, int B)
{
    const int b = blockIdx.x;
    const int t = threadIdx.x;
    __shared__ float s_beta[NB];
    __shared__ float s_rel[NJ][9];
    __shared__ float s_glob[NJ][9];
    __shared__ float s_j[NJ][3];

    if (t < NB) s_beta[t] = betas[b * NB + t];
    __syncthreads();

    if (t < NJ) {
        float rx = pose[b * 72 + t * 3 + 0];
        float ry = pose[b * 72 + t * 3 + 1];
        float rz = pose[b * 72 + t * 3 + 2];
        float th = sqrtf(rx * rx + ry * ry + rz * rz);
        float safe = (th < 1e-8f) ? 1.0f : th;
        float ax = rx / safe, ay = ry / safe, az = rz / safe;
        float s = sinf(th), c = cosf(th), omc = 1.0f - c;
        float aa = ax * ax + ay * ay + az * az;
        float K[9] = {0.f, -az, ay, az, 0.f, -ax, -ay, ax, 0.f};
        float A2[9] = {ax*ax - aa, ax*ay,      ax*az,
                       ay*ax,      ay*ay - aa, ay*az,
                       az*ax,      az*ay,      az*az - aa};
        #pragma unroll
        for (int r = 0; r < 3; ++r)
            #pragma unroll
            for (int cc = 0; cc < 3; ++cc)
                s_rel[t][r * 3 + cc] = ((r == cc) ? 1.0f : 0.0f)
                                     + s * K[r * 3 + cc] + omc * A2[r * 3 + cc];
        #pragma unroll
        for (int cc = 0; cc < 3; ++cc) {
            float acc = J_template[t * 3 + cc];
            #pragma unroll
            for (int q = 0; q < NB; ++q)
                acc = fmaf(J_shapedirs[(t * 3 + cc) * NB + q], s_beta[q], acc);
            s_j[t][cc] = acc;
        }
    }
    __syncthreads();

    if (t < NJ) {
        const int L = c_plen[t];
        float G[9];
        #pragma unroll
        for (int e = 0; e < 9; ++e) G[e] = s_rel[0][e];
        for (int sIdx = 1; sIdx < L; ++sIdx) {
            const int p = c_path[t][sIdx];
            float Tn[9];
            #pragma unroll
            for (int r = 0; r < 3; ++r)
                #pragma unroll
                for (int cc = 0; cc < 3; ++cc)
                    Tn[r * 3 + cc] = G[r * 3 + 0] * s_rel[p][0 * 3 + cc]
                                   + G[r * 3 + 1] * s_rel[p][1 * 3 + cc]
                                   + G[r * 3 + 2] * s_rel[p][2 * 3 + cc];
            #pragma unroll
            for (int e = 0; e < 9; ++e) G[e] = Tn[e];
        }
        #pragma unroll
        for (int e = 0; e < 9; ++e) s_glob[t][e] = G[e];
        #pragma unroll
        for (int e = 0; e < 9; ++e) glob_out[(size_t)b * 216 + t * 9 + e] = G[e];
    }
    __syncthreads();

    if (t < NJ) {
        const int L = c_plen[t];
        float px = s_j[0][0], py = s_j[0][1], pz = s_j[0][2];
        for (int sIdx = 1; sIdx < L; ++sIdx) {
            const int pk = c_path[t][sIdx];
            const int pp = c_path[t][sIdx - 1];
            float bx = s_j[pk][0] - s_j[pp][0];
            float by = s_j[pk][1] - s_j[pp][1];
            float bz = s_j[pk][2] - s_j[pp][2];
            px += s_glob[pp][0] * bx + s_glob[pp][1] * by + s_glob[pp][2] * bz;
            py += s_glob[pp][3] * bx + s_glob[pp][4] * by + s_glob[pp][5] * bz;
            pz += s_glob[pp][6] * bx + s_glob[pp][7] * by + s_glob[pp][8] * bz;
        }
        const float tx = trans[b * 3 + 0], ty = trans[b * 3 + 1], tz = trans[b * 3 + 2];
        joints_out[(size_t)b * 72 + t * 3 + 0] = px + tx;
        joints_out[(size_t)b * 72 + t * 3 + 1] = py + ty;
        joints_out[(size_t)b * 72 + t * 3 + 2] = pz + tz;
        const float jx = s_j[t][0], jy = s_j[t][1], jz = s_j[t][2];
        float T0 = px - (s_glob[t][0] * jx + s_glob[t][1] * jy + s_glob[t][2] * jz) + tx;
        float T1 = py - (s_glob[t][3] * jx + s_glob[t][4] * jy + s_glob[t][5] * jz) + ty;
        float T2 = pz - (s_glob[t][6] * jx + s_glob[t][7] * jy + s_glob[t][8] * jz) + tz;
        float* Ab = A_ws + ((size_t)b * NJ + t) * 12;
        Ab[0]  = s_glob[t][0]; Ab[1]  = s_glob[t][1]; Ab[2]  = s_glob[t][2]; Ab[3]  = T0;
        Ab[4]  = s_glob[t][3]; Ab[5]  = s_glob[t][4]; Ab[6]  = s_glob[t][5]; Ab[7]  = T1;
        Ab[8]  = s_glob[t][6]; Ab[9]  = s_glob[t][7]; Ab[10] = s_glob[t][8]; Ab[11] = T2;
    }
    __syncthreads();

    const int btg = b >> 4, bl = b & 15;
    for (int k = t; k < KP; k += 64) {
        float val;
        if (k < NB) val = s_beta[k];
        else if (k < KREAL) { const int p2 = k - NB; val = s_rel[1 + p2 / 9][p2 % 9]; }
        else val = 0.f;
        const int kt = k >> 5, kg = (k >> 3) & 3, i = k & 7;
        coeffF[(((size_t)kt * (B >> 4) + btg) * 64 + kg * 16 + bl) * 8 + i] = f2bf(val);
    }
}

// ---------------------------------------------------------------------------
// Kernel 3: certified MFMA GEMM1 + fp32 scalar LBS, restructured into TWO
// 32-batch passes so ep-LDS shrinks 52->25.3 KB (2 -> ~4-6 blocks/CU).
// Grid (B/64, 108) x 256 (4 waves), wave = vtile.
// ---------------------------------------------------------------------------
__global__ __launch_bounds__(256, 4)
void vert_kernel(const float4* __restrict__ dirsF, const float4* __restrict__ coeffF,
                 const float* __restrict__ A_ws, const float* __restrict__ v_template,
                 const float* __restrict__ weights, float* __restrict__ vert_out, int B)
{
    __shared__ float smem[6336];    // 25,344 B: dirs chunk (12KB) / ep[3][32][66]
    const int tid  = threadIdx.x;
    const int lane = tid & 63;
    const int w    = __builtin_amdgcn_readfirstlane(tid >> 6);   // 0..3
    const int vt   = w;
    const int vb4  = blockIdx.y * 4;     // global vtile base
    const int bblk = blockIdx.x;
    const int nbt  = B >> 4;

    f32x4 acc[3][4];
    #pragma unroll
    for (int c = 0; c < 3; ++c)
        #pragma unroll
        for (int bt = 0; bt < 4; ++bt) {
            acc[c][bt][0] = 0.f; acc[c][bt][1] = 0.f; acc[c][bt][2] = 0.f; acc[c][bt][3] = 0.f;
        }

    for (int kt = 0; kt < 7; ++kt) {
        __syncthreads();
        // stage 768 float4 of dirs chunk (12 KB): [c][vtl][lane]   (certified)
        #pragma unroll
        for (int s = 0; s < 3; ++s) {
            const int row = s * 256 + tid;
            const int ch = row >> 6, l2 = row & 63;
            *(float4*)&smem[row * 4] =
                dirsF[((size_t)(kt * 3 + (ch >> 2)) * NVT + vb4 + (ch & 3)) * 64 + l2];
        }
        __syncthreads();
        bf16x8 bq[4];
        #pragma unroll
        for (int bt = 0; bt < 4; ++bt)
            bq[bt] = *(const bf16x8*)&coeffF[((size_t)kt * nbt + bblk * 4 + bt) * 64 + lane];
        #pragma unroll
        for (int c = 0; c < 3; ++c) {
            const bf16x8 a = *(const bf16x8*)&smem[((c * 4 + vt) * 64 + lane) * 4];
            #pragma unroll
            for (int bt = 0; bt < 4; ++bt)
                acc[c][bt] = __builtin_amdgcn_mfma_f32_16x16x32_bf16(a, bq[bt], acc[c][bt], 0, 0, 0);
        }
    }

    // add v_template: C-frag rows v = (vb4+vt)*16 + (lane>>4)*4 + r   (certified)
    const int vrow0 = (vb4 + vt) * 16 + ((lane >> 4) << 2);
    #pragma unroll
    for (int c = 0; c < 3; ++c) {
        float tv[4];
        #pragma unroll
        for (int r = 0; r < 4; ++r) {
            const int v = vrow0 + r;
            tv[r] = (v < NV) ? v_template[(size_t)v * 3 + c] : 0.f;
        }
        #pragma unroll
        for (int bt = 0; bt < 4; ++bt) {
            acc[c][bt][0] += tv[0]; acc[c][bt][1] += tv[1];
            acc[c][bt][2] += tv[2]; acc[c][bt][3] += tv[3];
        }
    }

    // hoist skinning weights for this thread's vertex (v = lane within 64-tile)
    const int vglob = vb4 * 16 + lane;
    float wj[NJ];
    if (vglob < NV) {
        const float4* wp = (const float4*)(weights + (size_t)vglob * NJ);
        #pragma unroll
        for (int q = 0; q < 6; ++q) {
            const float4 t4 = wp[q];
            wj[q * 4 + 0] = t4.x; wj[q * 4 + 1] = t4.y; wj[q * 4 + 2] = t4.z; wj[q * 4 + 3] = t4.w;
        }
    }

    __syncthreads();   // all waves done reading dirs LDS

    // two passes of 32 batches: transpose C-frags -> ep, then scalar LBS
    for (int p = 0; p < 2; ++p) {
        if (p) __syncthreads();   // pass-0 readers done before overwrite
        #pragma unroll
        for (int c = 0; c < 3; ++c)
            #pragma unroll
            for (int half = 0; half < 2; ++half) {
                const int b32 = half * 16 + (lane & 15);
                const int vl  = vt * 16 + ((lane >> 4) << 2);
                const f32x4 av = acc[c][2 * p + half];
                #pragma unroll
                for (int r = 0; r < 4; ++r)
                    smem[(c * 32 + b32) * 66 + vl + r] = av[r];
            }
        __syncthreads();

        if (vglob < NV) {
            for (int i = 0; i < 8; ++i) {
                const int b32 = w * 8 + i;
                const int b = bblk * 64 + p * 32 + b32;
                const float4* Ab = (const float4*)(A_ws + (size_t)b * (NJ * 12));  // uniform
                float R0 = 0.f, R1 = 0.f, R2 = 0.f, R3 = 0.f, R4 = 0.f, R5 = 0.f,
                      R6 = 0.f, R7 = 0.f, R8 = 0.f, T0 = 0.f, T1 = 0.f, T2 = 0.f;
                #pragma unroll
                for (int jj = 0; jj < NJ; ++jj) {
                    const float wv = wj[jj];
                    const float4 a0 = Ab[jj * 3 + 0];
                    const float4 a1 = Ab[jj * 3 + 1];
                    const float4 a2 = Ab[jj * 3 + 2];
                    R0 = fmaf(wv, a0.x, R0); R1 = fmaf(wv, a0.y, R1); R2 = fmaf(wv, a0.z, R2); T0 = fmaf(wv, a0.w, T0);
                    R3 = fmaf(wv, a1.x, R3); R4 = fmaf(wv, a1.y, R4); R5 = fmaf(wv, a1.z, R5); T1 = fmaf(wv, a1.w, T1);
                    R6 = fmaf(wv, a2.x, R6); R7 = fmaf(wv, a2.y, R7); R8 = fmaf(wv, a2.z, R8); T2 = fmaf(wv, a2.w, T2);
                }
                const float vp0 = smem[(0 * 32 + b32) * 66 + lane];
                const float vp1 = smem[(1 * 32 + b32) * 66 + lane];
                const float vp2 = smem[(2 * 32 + b32) * 66 + lane];
                const float o0 = R0 * vp0 + R1 * vp1 + R2 * vp2 + T0;
                const float o1 = R3 * vp0 + R4 * vp1 + R5 * vp2 + T1;
                const float o2 = R6 * vp0 + R7 * vp1 + R8 * vp2 + T2;
                const size_t off = (size_t)b * (NV * 3) + (size_t)vglob * 3;
                vert_out[off + 0] = o0;
                vert_out[off + 1] = o1;
                vert_out[off + 2] = o2;
            }
        }
    }
}

// ---------------------------------------------------------------------------
extern "C" void kernel_launch(void* const* d_in, const int* in_sizes, int n_in,
                              void* d_out, int out_size, void* d_ws, size_t ws_size,
                              hipStream_t stream) {
    const float* pose        = (const float*)d_in[0];
    const float* betas       = (const float*)d_in[1];
    const float* trans       = (const float*)d_in[2];
    const float* v_template  = (const float*)d_in[3];
    const float* shapedirs   = (const float*)d_in[4];
    const float* posedirs    = (const float*)d_in[5];
    const float* J_template  = (const float*)d_in[6];
    const float* J_shapedirs = (const float*)d_in[7];
    const float* weights     = (const float*)d_in[8];
    const int B = in_sizes[0] / 72;   // 1024

    float* out = (float*)d_out;
    float* joints_out = out;                                        // B*72
    float* vert_out   = out + (size_t)B * 72;                       // B*NV*3
    float* glob_out   = out + (size_t)B * 72 + (size_t)B * NV * 3;  // B*216

    char* ws = (char*)d_ws;
    const size_t a_bytes     = (size_t)B * 288 * 4;                  // 1,179,648
    const size_t coeff_bytes = (size_t)7 * (B >> 4) * 64 * 16;       // 458,752
    float*          A_ws   = (float*)ws;
    unsigned short* coeffF = (unsigned short*)(ws + a_bytes);
    unsigned short* dirsF  = (unsigned short*)(ws + a_bytes + coeff_bytes);

    pack_kernel<<<dim3(NVT), 256, 0, stream>>>(shapedirs, posedirs, dirsF);
    prep_kernel<<<dim3(B), 64, 0, stream>>>(pose, betas, trans, J_template, J_shapedirs,
                                            joints_out, glob_out, A_ws, coeffF, B);
    vert_kernel<<<dim3(B / 64, 108), 256, 0, stream>>>((const float4*)dirsF, (const float4*)coeffF,
                                                       A_ws, v_template, weights, vert_out, B);
}